// Round 1
// baseline (60949.841 us; speedup 1.0000x reference)
//
#include <hip/hip_runtime.h>

#define TSTEPS 8192
#define NDIM   2048
#define NBLK   256
#define NTHR   256

// Device-coherent (agent-scope, sc1) accessors: bypass the non-coherent
// per-XCD L2s so cross-XCD state exchange needs no cache-maintenance fences.
__device__ __forceinline__ unsigned ld_flag(const unsigned* p) {
  return __hip_atomic_load((unsigned*)p, __ATOMIC_RELAXED, __HIP_MEMORY_SCOPE_AGENT);
}
__device__ __forceinline__ void st_flag(unsigned* p, unsigned v) {
  __hip_atomic_store(p, v, __ATOMIC_RELAXED, __HIP_MEMORY_SCOPE_AGENT);
}
__device__ __forceinline__ float ld_x(const float* p) {
  return __hip_atomic_load((float*)p, __ATOMIC_RELAXED, __HIP_MEMORY_SCOPE_AGENT);
}
__device__ __forceinline__ void st_x(float* p, float v) {
  __hip_atomic_store(p, v, __ATOMIC_RELAXED, __HIP_MEMORY_SCOPE_AGENT);
}

__global__ void __launch_bounds__(NTHR) esn_persistent(
    const float* __restrict__ u,
    const float* __restrict__ W_in,
    const float* __restrict__ W_res,
    const int* __restrict__ washout_p,
    float* __restrict__ out,
    unsigned* __restrict__ ws)
{
  const int tid  = threadIdx.x;
  const int bid  = blockIdx.x;
  const int wave = tid >> 6;
  const int lane = tid & 63;
  const int row0 = bid * 8 + wave * 2;   // this wave owns rows row0, row0+1
  const int washout = washout_p[0];

  // ws layout (zeroed by hipMemsetAsync each launch):
  //   [0   .. 1KB)  : flags[256]   (block b arrived at step flags[b])
  //   [2KB .. 2KB+4): abort word
  //   [4KB .. 20KB) : x double buffer, 2 * 2048 f32  (x0 = zeros)
  unsigned* flags  = ws;
  unsigned* abortw = ws + 512;
  float*    xbuf   = (float*)(ws + 1024);

  __shared__ float x_lds[NDIM];
  __shared__ int s_abort;
  if (tid == 0) s_abort = 0;

  // Preload this wave's 2 rows of W_res into registers (read HBM exactly once).
  // lane covers float4 chunks c4 = k*64 + lane, k = 0..7  (2048 f32 per row).
  float4 w0[8], w1[8];
  {
    const float4* Wr0 = (const float4*)(W_res + (size_t)row0 * NDIM);
    const float4* Wr1 = (const float4*)(W_res + (size_t)(row0 + 1) * NDIM);
#pragma unroll
    for (int k = 0; k < 8; ++k) {
      w0[k] = Wr0[k * 64 + lane];
      w1[k] = Wr1[k * 64 + lane];
    }
  }
  const float win0 = W_in[row0];
  const float win1 = W_in[row0 + 1];

  for (int t = 0; t < TSTEPS; ++t) {
    // ---- distributed barrier: wait until every block published x_t ----
    {
      const unsigned target = (unsigned)t;
      unsigned g = 0;
      bool ab = false;
      while (ld_flag(&flags[tid]) < target) {
        if ((++g & 1023u) == 0u) {
          if (ld_flag(abortw) != 0u) { ab = true; break; }
          if (g > (1u << 20))        { st_flag(abortw, 1u); ab = true; break; }
        }
      }
      if (ab) s_abort = 1;
    }
    __syncthreads();
    if (s_abort) return;   // uniform exit: fail loudly instead of hanging

    // ---- stage x_t into LDS (device-coherent loads, coalesced) ----
    {
      const float* xsrc = xbuf + (t & 1) * NDIM;
#pragma unroll
      for (int k = 0; k < 8; ++k) {
        const int c = tid + NTHR * k;
        x_lds[c] = ld_x(xsrc + c);
      }
    }
    __syncthreads();

    // ---- 2 dot products per wave: W rows from VGPRs, x from LDS ----
    float a0 = 0.f, a1 = 0.f;
    const float4* x4 = (const float4*)x_lds;
#pragma unroll
    for (int k = 0; k < 8; ++k) {
      const float4 xv = x4[k * 64 + lane];
      a0 += w0[k].x * xv.x; a0 += w0[k].y * xv.y;
      a0 += w0[k].z * xv.z; a0 += w0[k].w * xv.w;
      a1 += w1[k].x * xv.x; a1 += w1[k].y * xv.y;
      a1 += w1[k].z * xv.z; a1 += w1[k].w * xv.w;
    }
#pragma unroll
    for (int off = 32; off > 0; off >>= 1) {
      a0 += __shfl_xor(a0, off, 64);
      a1 += __shfl_xor(a1, off, 64);
    }

    // ---- finalize + publish x_{t+1}; stream output row ----
    if (lane == 0) {
      const float ut  = u[t];
      const float xn0 = tanhf(win0 * ut + a0);
      const float xn1 = tanhf(win1 * ut + a1);
      float* xdst = xbuf + ((t + 1) & 1) * NDIM;
      st_x(xdst + row0,     xn0);
      st_x(xdst + row0 + 1, xn1);
      if (t >= washout) {
        float* orow = out + (size_t)(t - washout) * NDIM;
        orow[row0]     = xn0;
        orow[row0 + 1] = xn1;
      }
    }

    // Drain this wave's stores, join waves (compiler drains each wave's vmcnt
    // before s_barrier), then publish arrival flag — data strictly precedes flag.
    asm volatile("s_waitcnt vmcnt(0)" ::: "memory");
    __syncthreads();
    if (tid == 0) st_flag(&flags[bid], (unsigned)(t + 1));
  }
}

extern "C" void kernel_launch(void* const* d_in, const int* in_sizes, int n_in,
                              void* d_out, int out_size, void* d_ws, size_t ws_size,
                              hipStream_t stream) {
  const float* u       = (const float*)d_in[0];
  const float* W_in    = (const float*)d_in[1];
  const float* W_res   = (const float*)d_in[2];
  const int*   washout = (const int*)d_in[3];
  float*       out     = (float*)d_out;

  // Reset flags / abort / x double-buffer (x0 = zeros). Captured in the graph,
  // so every replay starts from identical state.
  hipMemsetAsync(d_ws, 0, 20480, stream);

  esn_persistent<<<dim3(NBLK), dim3(NTHR), 0, stream>>>(
      u, W_in, W_res, washout, out, (unsigned*)d_ws);
}

// Round 3
// 33230.356 us; speedup vs baseline: 1.8342x; 1.8342x over previous
//
#include <hip/hip_runtime.h>

#define TSTEPS 8192
#define NDIM   2048
#define NBLK   128
#define NTHR   512
#define RPB    16     // rows per block = NDIM/NBLK

typedef float f32x4 __attribute__((ext_vector_type(4)));

// Agent-scope (device-coherent, sc1) accessors — coherence point is the
// shared LLC, bypassing the non-coherent per-XCD L2s.
__device__ __forceinline__ unsigned ld_flag(const unsigned* p) {
  return __hip_atomic_load((unsigned*)p, __ATOMIC_RELAXED, __HIP_MEMORY_SCOPE_AGENT);
}
__device__ __forceinline__ void st_flag(unsigned* p, unsigned v) {
  __hip_atomic_store(p, v, __ATOMIC_RELAXED, __HIP_MEMORY_SCOPE_AGENT);
}
// 16B device-coherent load, completion fused in-asm (one load per thread, so
// the serial waitcnt costs nothing extra).
__device__ __forceinline__ f32x4 ld_x4_agent(const f32x4* p) {
  f32x4 r;
  asm volatile("global_load_dwordx4 %0, %1, off sc1\n\ts_waitcnt vmcnt(0)"
               : "=v"(r) : "v"(p) : "memory");
  return r;
}
__device__ __forceinline__ void st_x4_agent(f32x4* p, f32x4 v) {
  asm volatile("global_store_dwordx4 %0, %1, off sc1" :: "v"(p), "v"(v) : "memory");
}

__global__ void __launch_bounds__(NTHR, 1) esn_persistent(
    const float* __restrict__ u,
    const float* __restrict__ W_in,
    const float* __restrict__ W_res,
    const int* __restrict__ washout_p,
    float* __restrict__ out,
    unsigned* __restrict__ ws)
{
  const int tid  = threadIdx.x;
  const int bid  = blockIdx.x;
  const int wave = tid >> 6;
  const int lane = tid & 63;
  const int row0 = bid * RPB + wave * 2;   // this wave owns rows row0, row0+1
  const int washout = washout_p[0];

  // ws layout (zeroed by hipMemsetAsync each launch):
  //   u32[0..128)   : flags   (block b has published x_{flags[b]})
  //   u32[144]      : abort word (own line)
  //   byte 1024+    : x double buffer, 2 * 2048 f32  (x0 = zeros)
  unsigned* flags  = ws;
  unsigned* abortw = ws + 144;
  float*    xbuf   = (float*)((char*)ws + 1024);

  __shared__ float x_lds[NDIM];
  __shared__ float xout[RPB];         // block's 16 new state values (one 64B line)
  __shared__ int   s_abort;
  if (tid == 0) s_abort = 0;

  // Preload this wave's 2 rows of W_res into registers (HBM read exactly once).
  float4 w0[8], w1[8];
  {
    const float4* Wr0 = (const float4*)(W_res + (size_t)row0 * NDIM);
    const float4* Wr1 = (const float4*)(W_res + (size_t)(row0 + 1) * NDIM);
#pragma unroll
    for (int k = 0; k < 8; ++k) {
      w0[k] = Wr0[k * 64 + lane];
      w1[k] = Wr1[k * 64 + lane];
    }
  }
  const float win0 = W_in[row0];
  const float win1 = W_in[row0 + 1];

  for (int t = 0; t < TSTEPS; ++t) {
    // ---- barrier: wave 0 polls all 128 flags with ONE coalesced wave-read ----
    if (tid < 64) {
      const unsigned target = (unsigned)t;
      unsigned g = 0;
      for (;;) {
        const unsigned f0 = ld_flag(flags + lane);
        const unsigned f1 = ld_flag(flags + 64 + lane);
        if (__all((f0 >= target) && (f1 >= target))) break;
        if ((++g & 255u) == 0u) {
          if (ld_flag(abortw) != 0u) { s_abort = 1; break; }
          if (g > (1u << 20))        { st_flag(abortw, 1u); s_abort = 1; break; }
        }
      }
    }
    __syncthreads();                       // S1
    if (s_abort) return;                   // fail loudly instead of hanging

    // ---- stage x_t into LDS: one coalesced 16B agent-load per thread ----
    {
      const f32x4* xsrc = (const f32x4*)(xbuf + (t & 1) * NDIM);
      const f32x4 xv = ld_x4_agent(xsrc + tid);
      ((f32x4*)x_lds)[tid] = xv;
    }
    const float ut = u[t];                 // uniform, cached
    __syncthreads();                       // S2

    // ---- 2 dot products per wave: W from VGPRs, x from LDS ----
    float a0 = 0.f, a1 = 0.f;
    const float4* x4 = (const float4*)x_lds;
#pragma unroll
    for (int k = 0; k < 8; ++k) {
      const float4 xv = x4[k * 64 + lane];
      a0 += w0[k].x * xv.x; a0 += w0[k].y * xv.y;
      a0 += w0[k].z * xv.z; a0 += w0[k].w * xv.w;
      a1 += w1[k].x * xv.x; a1 += w1[k].y * xv.y;
      a1 += w1[k].z * xv.z; a1 += w1[k].w * xv.w;
    }
#pragma unroll
    for (int off = 32; off > 0; off >>= 1) {
      a0 += __shfl_xor(a0, off, 64);
      a1 += __shfl_xor(a1, off, 64);
    }
    if (lane < 2) {                        // split the two tanh across 2 lanes
      const float a  = (lane == 0) ? a0 : a1;
      const float wi = (lane == 0) ? win0 : win1;
      xout[wave * 2 + lane] = tanhf(wi * ut + a);
    }
    __syncthreads();                       // S3

    // ---- publish: one full-line data store, drain, then one flag dword ----
    if (tid < 64) {
      if (lane < 4) {                      // 4 lanes x dwordx4 = one 64B line
        f32x4* xdst = (f32x4*)(xbuf + ((t + 1) & 1) * NDIM) + bid * 4;
        st_x4_agent(xdst + lane, ((const f32x4*)xout)[lane]);
      }
      if (t >= washout && lane >= 4 && lane < 8) {   // output row: plain cached line
        float4* orow = (float4*)(out + (size_t)(t - washout) * NDIM) + bid * 4;
        orow[lane - 4] = ((const float4*)xout)[lane - 4];
      }
      asm volatile("s_waitcnt vmcnt(0)" ::: "memory");  // data strictly before flag
      if (lane == 0) st_flag(&flags[bid], (unsigned)(t + 1));
    }
  }
}

extern "C" void kernel_launch(void* const* d_in, const int* in_sizes, int n_in,
                              void* d_out, int out_size, void* d_ws, size_t ws_size,
                              hipStream_t stream) {
  const float* u       = (const float*)d_in[0];
  const float* W_in    = (const float*)d_in[1];
  const float* W_res   = (const float*)d_in[2];
  const int*   washout = (const int*)d_in[3];
  float*       out     = (float*)d_out;

  // Reset flags / abort / x double-buffer (x0 = zeros). Captured in the graph,
  // so every replay starts from identical state.
  (void)hipMemsetAsync(d_ws, 0, 20480, stream);

  esn_persistent<<<dim3(NBLK), dim3(NTHR), 0, stream>>>(
      u, W_in, W_res, washout, out, (unsigned*)d_ws);
}

// Round 4
// 18202.507 us; speedup vs baseline: 3.3484x; 1.8256x over previous
//
#include <hip/hip_runtime.h>

#define TSTEPS 8192
#define NDIM   2048
#define NBLK   128
#define NTHR   512
#define RPB    16     // rows per block = NDIM/NBLK

typedef float f32x4 __attribute__((ext_vector_type(4)));
typedef int   i32x4 __attribute__((ext_vector_type(4)));
typedef float f32x2 __attribute__((ext_vector_type(2)));

// Agent-scope (device-coherent, sc1) ops — coherence point is the shared LLC.
__device__ __forceinline__ unsigned ld_u32_agent(const unsigned* p) {
  return __hip_atomic_load((unsigned*)p, __ATOMIC_RELAXED, __HIP_MEMORY_SCOPE_AGENT);
}
__device__ __forceinline__ void st_u32_agent(unsigned* p, unsigned v) {
  __hip_atomic_store(p, v, __ATOMIC_RELAXED, __HIP_MEMORY_SCOPE_AGENT);
}
// Two 16B device-coherent loads sharing ONE completion wait (single round trip).
__device__ __forceinline__ void ld_2x4_agent(const i32x4* p0, const i32x4* p1,
                                             i32x4& r0, i32x4& r1) {
  asm volatile("global_load_dwordx4 %0, %2, off sc1\n\t"
               "global_load_dwordx4 %1, %3, off sc1\n\t"
               "s_waitcnt vmcnt(0)"
               : "=&v"(r0), "=&v"(r1) : "v"(p0), "v"(p1) : "memory");
}
__device__ __forceinline__ void st_x4_agent(f32x4* p, f32x4 v) {
  asm volatile("global_store_dwordx4 %0, %1, off sc1" :: "v"(p), "v"(v) : "memory");
}

__global__ void __launch_bounds__(NTHR, 1) esn_persistent(
    const float* __restrict__ u,
    const float* __restrict__ W_in,
    const float* __restrict__ W_res,
    const int* __restrict__ washout_p,
    float* __restrict__ out,
    unsigned* __restrict__ ws)
{
  const int tid  = threadIdx.x;
  const int bid  = blockIdx.x;
  const int wave = tid >> 6;
  const int lane = tid & 63;
  const int row0 = bid * RPB + wave * 2;   // this wave owns rows row0, row0+1
  const int washout = washout_p[0];

  // ws layout (zeroed by hipMemsetAsync each launch):
  //   u32[144]      : abort word (own line)
  //   byte 1024+    : tagged state, 2 parity buffers of 2048 (f32 val, u32 tag)
  //                   pairs: pair[2i] = x[i] bits, pair[2i+1] = tag
  unsigned* abortw = ws + 144;
  float* pair0 = (float*)((char*)ws + 1024);
  float* pair1 = pair0 + 2 * NDIM;

  __shared__ __align__(16) float x_lds[NDIM];
  __shared__ __align__(16) float xpair_lds[2 * RPB];  // block's 16 (val,tag) pairs
  __shared__ __align__(16) float xval_lds[RPB];       // block's 16 values (out row)
  __shared__ int s_abort;
  if (tid == 0) s_abort = 0;

  // ---- W preload: 16 NAMED f32x4 regs (2 rows/wave). Named scalars cannot be
  // demoted to scratch (round-3 VGPR_Count=48 proved float4 w[8] arrays were). ----
  const f32x4* Wr0 = (const f32x4*)(W_res + (size_t)row0 * NDIM) + lane;
  const f32x4* Wr1 = (const f32x4*)(W_res + (size_t)(row0 + 1) * NDIM) + lane;
  const f32x4 w00 = Wr0[0 * 64], w01 = Wr0[1 * 64], w02 = Wr0[2 * 64], w03 = Wr0[3 * 64];
  const f32x4 w04 = Wr0[4 * 64], w05 = Wr0[5 * 64], w06 = Wr0[6 * 64], w07 = Wr0[7 * 64];
  const f32x4 w10 = Wr1[0 * 64], w11 = Wr1[1 * 64], w12 = Wr1[2 * 64], w13 = Wr1[3 * 64];
  const f32x4 w14 = Wr1[4 * 64], w15 = Wr1[5 * 64], w16 = Wr1[6 * 64], w17 = Wr1[7 * 64];
  const float win0 = W_in[row0];
  const float win1 = W_in[row0 + 1];

  for (int t = 0; t < TSTEPS; ++t) {
    // ---- fused poll+stage: retry the staging load until all tags == t.
    // One LLC round trip replaces round-3's {flag RT + store-ack + data RT}. ----
    const i32x4* src = (const i32x4*)((t & 1) ? pair1 : pair0);
    const int want = t;
    i32x4 r0, r1;
    bool ok;
    {
      unsigned g = 0;
      do {
        ld_2x4_agent(src + tid, src + NTHR + tid, r0, r1);
        ok = (r0.y == want) & (r0.w == want) & (r1.y == want) & (r1.w == want);
        if (!ok && ((++g & 255u) == 0u)) {
          if (ld_u32_agent(abortw) != 0u) break;
          if (g > (1u << 20)) { st_u32_agent(abortw, 1u); break; }
        }
      } while (!ok);
    }
    if (!ok) s_abort = 1;
    {
      f32x2 v01, v23;
      v01.x = __int_as_float(r0.x); v01.y = __int_as_float(r0.z);
      v23.x = __int_as_float(r1.x); v23.y = __int_as_float(r1.z);
      ((f32x2*)x_lds)[tid]        = v01;   // x[2tid], x[2tid+1]
      ((f32x2*)x_lds)[NTHR + tid] = v23;   // x[1024+2tid], x[1024+2tid+1]
    }
    const float ut = u[t];                 // uniform, cached; hides under S_a
    __syncthreads();                       // S_a
    if (s_abort) return;                   // fail loudly instead of hanging

    // ---- 2 dot products per wave: W from named VGPRs, x from LDS.
    // 4 accumulators → 16-deep FMA chains. ----
    float a0 = 0.f, b0 = 0.f, a1 = 0.f, b1 = 0.f;
    const f32x4* x4v = (const f32x4*)x_lds + lane;
#define ESN_DOT(WA, WB, K, A, B) { const f32x4 xv = x4v[(K) * 64];            \
      A += WA.x * xv.x; A += WA.y * xv.y; A += WA.z * xv.z; A += WA.w * xv.w; \
      B += WB.x * xv.x; B += WB.y * xv.y; B += WB.z * xv.z; B += WB.w * xv.w; }
    ESN_DOT(w00, w10, 0, a0, a1) ESN_DOT(w01, w11, 1, b0, b1)
    ESN_DOT(w02, w12, 2, a0, a1) ESN_DOT(w03, w13, 3, b0, b1)
    ESN_DOT(w04, w14, 4, a0, a1) ESN_DOT(w05, w15, 5, b0, b1)
    ESN_DOT(w06, w16, 6, a0, a1) ESN_DOT(w07, w17, 7, b0, b1)
#undef ESN_DOT
    const float s0 = a0 + b0;
    const float s1 = a1 + b1;
    // 7-shfl reduce: fold 64→32 for both rows, route row1 to upper half, butterfly.
    const float c0 = s0 + __shfl_xor(s0, 32, 64);
    const float c1 = s1 + __shfl_xor(s1, 32, 64);
    float c = (lane < 32) ? c0 : c1;
#pragma unroll
    for (int off = 16; off > 0; off >>= 1) c += __shfl_xor(c, off, 64);

    if ((lane & 31) == 0) {                // lane 0 → row0, lane 32 → row1
      const float wi  = (lane == 0) ? win0 : win1;
      const float pre = wi * ut + c;
      const float e2  = __expf(2.0f * pre);            // tanh = 1 - 2/(e^2x + 1)
      const float th  = 1.0f - __fdividef(2.0f, e2 + 1.0f);
      const int   i   = wave * 2 + (lane >> 5);
      xval_lds[i] = th;
      ((f32x2*)xpair_lds)[i] = (f32x2){ th, __int_as_float(t + 1) };
    }
    __syncthreads();                       // S_b

    // ---- publish: fire-and-forget full-line tagged stores; no ack, no flag ----
    if (tid < 12) {
      if (tid < 8) {                       // 8 x dwordx4 = 32 floats = 16 pairs
        f32x4* dst = (f32x4*)(((t + 1) & 1) ? pair1 : pair0) + bid * 8 + tid;
        st_x4_agent(dst, ((const f32x4*)xpair_lds)[tid]);
      } else if (t >= washout) {           // output row: plain cached stores
        float4* orow = (float4*)(out + (size_t)(t - washout) * NDIM) + bid * 4 + (tid - 8);
        const f32x4 vv = ((const f32x4*)xval_lds)[tid - 8];
        float4 v; v.x = vv.x; v.y = vv.y; v.z = vv.z; v.w = vv.w;
        *orow = v;
      }
    }
  }
}

extern "C" void kernel_launch(void* const* d_in, const int* in_sizes, int n_in,
                              void* d_out, int out_size, void* d_ws, size_t ws_size,
                              hipStream_t stream) {
  const float* u       = (const float*)d_in[0];
  const float* W_in    = (const float*)d_in[1];
  const float* W_res   = (const float*)d_in[2];
  const int*   washout = (const int*)d_in[3];
  float*       out     = (float*)d_out;

  // Zero abort word + both tagged parity buffers (tag 0 == valid x0 = zeros).
  // Captured in the graph, so every replay starts from identical state.
  (void)hipMemsetAsync(d_ws, 0, 1024 + 4 * 2 * NDIM * 2, stream);

  esn_persistent<<<dim3(NBLK), dim3(NTHR), 0, stream>>>(
      u, W_in, W_res, washout, out, (unsigned*)d_ws);
}

// Round 5
// 18121.851 us; speedup vs baseline: 3.3633x; 1.0045x over previous
//
#include <hip/hip_runtime.h>

#define TSTEPS 8192
#define NDIM   2048
#define NBLK   128
#define NTHR   512
#define RPB    16     // rows per block = NDIM/NBLK

typedef float f32x4 __attribute__((ext_vector_type(4)));
typedef int   i32x4 __attribute__((ext_vector_type(4)));
typedef float f32x2 __attribute__((ext_vector_type(2)));

// Agent-scope (device-coherent, sc1) ops — coherence point is the shared LLC.
__device__ __forceinline__ unsigned ld_u32_agent(const unsigned* p) {
  return __hip_atomic_load((unsigned*)p, __ATOMIC_RELAXED, __HIP_MEMORY_SCOPE_AGENT);
}
__device__ __forceinline__ void st_u32_agent(unsigned* p, unsigned v) {
  __hip_atomic_store(p, v, __ATOMIC_RELAXED, __HIP_MEMORY_SCOPE_AGENT);
}
// Two 16B device-coherent loads sharing ONE completion wait (single round trip).
__device__ __forceinline__ void ld_2x4_agent(const i32x4* p0, const i32x4* p1,
                                             i32x4& r0, i32x4& r1) {
  asm volatile("global_load_dwordx4 %0, %2, off sc1\n\t"
               "global_load_dwordx4 %1, %3, off sc1\n\t"
               "s_waitcnt vmcnt(0)"
               : "=&v"(r0), "=&v"(r1) : "v"(p0), "v"(p1) : "memory");
}
__device__ __forceinline__ void st_x4_agent(f32x4* p, f32x4 v) {
  asm volatile("global_store_dwordx4 %0, %1, off sc1" :: "v"(p), "v"(v) : "memory");
}
// Pin a value into a VGPR quad: the asm result is opaque, so the compiler
// cannot re-materialize it by sinking the originating load into the loop
// (round-3/4 VGPR_Count=48/52 proved it was doing exactly that).
#define PIN4(v) asm volatile("" : "+v"(v))

__global__ void __launch_bounds__(NTHR, 1) esn_persistent(
    const float* __restrict__ u,
    const float* __restrict__ W_in,
    const float* __restrict__ W_res,
    const int* __restrict__ washout_p,
    float* __restrict__ out,
    unsigned* __restrict__ ws)
{
  const int tid  = threadIdx.x;
  const int bid  = blockIdx.x;
  const int wave = tid >> 6;
  const int lane = tid & 63;
  const int row0 = bid * RPB + wave * 2;   // this wave owns rows row0, row0+1
  const int washout = washout_p[0];

  // ws layout (zeroed by hipMemsetAsync each launch):
  //   u32[144]      : abort word (own line)
  //   byte 1024+    : tagged state, 2 parity buffers of 2048 (f32 val, u32 tag)
  //                   pairs: pair[2i] = x[i] bits, pair[2i+1] = tag
  unsigned* abortw = ws + 144;
  float* pair0 = (float*)((char*)ws + 1024);
  float* pair1 = pair0 + 2 * NDIM;

  __shared__ __align__(16) float x_lds[NDIM];
  __shared__ __align__(16) float xpair_lds[2 * RPB];  // block's 16 (val,tag) pairs
  __shared__ __align__(16) float xval_lds[RPB];       // block's 16 values (out row)
  __shared__ int s_abort;
  if (tid == 0) s_abort = 0;

  // ---- W preload into 16 named, PINNED f32x4 regs (2 rows/wave, 64 VGPRs). ----
  const f32x4* Wr0 = (const f32x4*)(W_res + (size_t)row0 * NDIM) + lane;
  const f32x4* Wr1 = (const f32x4*)(W_res + (size_t)(row0 + 1) * NDIM) + lane;
  f32x4 w00 = Wr0[0 * 64], w01 = Wr0[1 * 64], w02 = Wr0[2 * 64], w03 = Wr0[3 * 64];
  f32x4 w04 = Wr0[4 * 64], w05 = Wr0[5 * 64], w06 = Wr0[6 * 64], w07 = Wr0[7 * 64];
  f32x4 w10 = Wr1[0 * 64], w11 = Wr1[1 * 64], w12 = Wr1[2 * 64], w13 = Wr1[3 * 64];
  f32x4 w14 = Wr1[4 * 64], w15 = Wr1[5 * 64], w16 = Wr1[6 * 64], w17 = Wr1[7 * 64];
  PIN4(w00); PIN4(w01); PIN4(w02); PIN4(w03);
  PIN4(w04); PIN4(w05); PIN4(w06); PIN4(w07);
  PIN4(w10); PIN4(w11); PIN4(w12); PIN4(w13);
  PIN4(w14); PIN4(w15); PIN4(w16); PIN4(w17);
  const float win0 = W_in[row0];
  const float win1 = W_in[row0 + 1];

  for (int t = 0; t < TSTEPS; ++t) {
    // ---- fused poll+stage: retry the staging load until all tags == t.
    // One LLC round trip replaces {flag RT + store-ack + data RT}. ----
    const i32x4* src = (const i32x4*)((t & 1) ? pair1 : pair0);
    const int want = t;
    i32x4 r0, r1;
    bool ok;
    {
      unsigned g = 0;
      do {
        ld_2x4_agent(src + tid, src + NTHR + tid, r0, r1);
        ok = (r0.y == want) & (r0.w == want) & (r1.y == want) & (r1.w == want);
        if (!ok && ((++g & 255u) == 0u)) {
          if (ld_u32_agent(abortw) != 0u) break;
          if (g > (1u << 20)) { st_u32_agent(abortw, 1u); break; }
        }
      } while (!ok);
    }
    if (!ok) s_abort = 1;
    {
      f32x2 v01, v23;
      v01.x = __int_as_float(r0.x); v01.y = __int_as_float(r0.z);
      v23.x = __int_as_float(r1.x); v23.y = __int_as_float(r1.z);
      ((f32x2*)x_lds)[tid]        = v01;   // x[2tid], x[2tid+1]
      ((f32x2*)x_lds)[NTHR + tid] = v23;   // x[1024+2tid], x[1024+2tid+1]
    }
    const float ut = u[t];                 // uniform, cached; hides under S_a
    __syncthreads();                       // S_a
    if (s_abort) return;                   // fail loudly instead of hanging

    // ---- 2 dot products per wave: W from pinned VGPRs, x from LDS.
    // 4 accumulators → 16-deep FMA chains. ----
    float a0 = 0.f, b0 = 0.f, a1 = 0.f, b1 = 0.f;
    const f32x4* x4v = (const f32x4*)x_lds + lane;
#define ESN_DOT(WA, WB, K, A, B) { const f32x4 xv = x4v[(K) * 64];            \
      A += WA.x * xv.x; A += WA.y * xv.y; A += WA.z * xv.z; A += WA.w * xv.w; \
      B += WB.x * xv.x; B += WB.y * xv.y; B += WB.z * xv.z; B += WB.w * xv.w; }
    ESN_DOT(w00, w10, 0, a0, a1) ESN_DOT(w01, w11, 1, b0, b1)
    ESN_DOT(w02, w12, 2, a0, a1) ESN_DOT(w03, w13, 3, b0, b1)
    ESN_DOT(w04, w14, 4, a0, a1) ESN_DOT(w05, w15, 5, b0, b1)
    ESN_DOT(w06, w16, 6, a0, a1) ESN_DOT(w07, w17, 7, b0, b1)
#undef ESN_DOT
    const float s0 = a0 + b0;
    const float s1 = a1 + b1;
    // 7-shfl reduce: fold 64→32 for both rows, route row1 to upper half, butterfly.
    const float c0 = s0 + __shfl_xor(s0, 32, 64);
    const float c1 = s1 + __shfl_xor(s1, 32, 64);
    float c = (lane < 32) ? c0 : c1;
#pragma unroll
    for (int off = 16; off > 0; off >>= 1) c += __shfl_xor(c, off, 64);

    if ((lane & 31) == 0) {                // lane 0 → row0, lane 32 → row1
      const float wi  = (lane == 0) ? win0 : win1;
      const float pre = wi * ut + c;
      const float e2  = __expf(2.0f * pre);            // tanh = 1 - 2/(e^2x + 1)
      const float th  = 1.0f - __fdividef(2.0f, e2 + 1.0f);
      const int   i   = wave * 2 + (lane >> 5);
      xval_lds[i] = th;
      ((f32x2*)xpair_lds)[i] = (f32x2){ th, __int_as_float(t + 1) };
    }
    __syncthreads();                       // S_b

    // ---- publish: fire-and-forget full-line tagged stores; no ack, no flag ----
    if (tid < 12) {
      if (tid < 8) {                       // 8 x dwordx4 = 32 floats = 16 pairs
        f32x4* dst = (f32x4*)(((t + 1) & 1) ? pair1 : pair0) + bid * 8 + tid;
        st_x4_agent(dst, ((const f32x4*)xpair_lds)[tid]);
      } else if (t >= washout) {           // output row: plain cached stores
        float4* orow = (float4*)(out + (size_t)(t - washout) * NDIM) + bid * 4 + (tid - 8);
        const f32x4 vv = ((const f32x4*)xval_lds)[tid - 8];
        float4 v; v.x = vv.x; v.y = vv.y; v.z = vv.z; v.w = vv.w;
        *orow = v;
      }
    }
  }
}

extern "C" void kernel_launch(void* const* d_in, const int* in_sizes, int n_in,
                              void* d_out, int out_size, void* d_ws, size_t ws_size,
                              hipStream_t stream) {
  const float* u       = (const float*)d_in[0];
  const float* W_in    = (const float*)d_in[1];
  const float* W_res   = (const float*)d_in[2];
  const int*   washout = (const int*)d_in[3];
  float*       out     = (float*)d_out;

  // Zero abort word + both tagged parity buffers (tag 0 == valid x0 = zeros).
  // Captured in the graph, so every replay starts from identical state.
  (void)hipMemsetAsync(d_ws, 0, 1024 + 4 * 2 * NDIM * 2, stream);

  esn_persistent<<<dim3(NBLK), dim3(NTHR), 0, stream>>>(
      u, W_in, W_res, washout, out, (unsigned*)d_ws);
}